// Round 1
// baseline (397.665 us; speedup 1.0000x reference)
//
#include <hip/hip_runtime.h>
#include <math.h>

// Problem constants (match reference)
#define BB 256
#define WD 19
#define HD 19
#define AD 5
#define CD 80
#define TD 20
// N1 = B*W*H*A
#define N1 462080
#define NCLS (N1 * CD)        // 36,966,400
#define NPRED (N1 * 5)        // 2,310,400

__device__ __forceinline__ float sigmoidf_(float x) {
    return 1.0f / (1.0f + expf(-x));
}

__device__ __forceinline__ void wave_atomic_add(double* dst, float v) {
    // 64-lane butterfly-free down-reduce
    for (int off = 32; off > 0; off >>= 1) v += __shfl_down(v, off, 64);
    if ((threadIdx.x & 63) == 0) atomicAdd(dst, (double)v);
}

// ws layout (doubles):
// [0] sum(cls^2)  [1] sum(cls at c==79)  [2] sum(conf^2) base
// [3] noobj removed  [4] obj  [5] prior  [6] true  [7] score corr
__global__ void yolo_base_reduce(const float* __restrict__ cls,
                                 const float* __restrict__ pred,
                                 double* __restrict__ ws) {
    const int tid = blockIdx.x * blockDim.x + threadIdx.x;
    const int stride = gridDim.x * blockDim.x;

    float sumsq = 0.0f, sum79 = 0.0f, conf2 = 0.0f;

    // cls_score: NCLS floats = NCLS/4 float4s. Channel of element (4i+k) is (4i+k)%80.
    // Channel 79 occurs in float4 i at lane w iff i % 20 == 19.
    const float4* cls4 = reinterpret_cast<const float4*>(cls);
    const int nc4 = NCLS / 4;
    for (int i = tid; i < nc4; i += stride) {
        float4 v = cls4[i];
        sumsq += v.x * v.x + v.y * v.y + v.z * v.z + v.w * v.w;
        if (i % 20 == 19) sum79 += v.w;
    }

    // pred_object: channel (4i+k)%5 == 4  =>  k = (i+4)%5 (k==4 means none in this float4)
    const float4* p4 = reinterpret_cast<const float4*>(pred);
    const int np4 = NPRED / 4;
    for (int i = tid; i < np4; i += stride) {
        float4 v = p4[i];
        int k = (i + 4) % 5;
        if (k < 4) {
            float x = (k == 0) ? v.x : (k == 1) ? v.y : (k == 2) ? v.z : v.w;
            float c = sigmoidf_(x);
            conf2 += c * c;
        }
    }

    wave_atomic_add(&ws[0], sumsq);
    wave_atomic_add(&ws[1], sum79);
    wave_atomic_add(&ws[2], conf2);
}

__global__ void yolo_corrections(const float* __restrict__ cls,
                                 const float* __restrict__ pred,
                                 const float* __restrict__ tobj,
                                 const float* __restrict__ tlab,
                                 const float* __restrict__ anchors,
                                 const float* __restrict__ fm_cord,
                                 const float* __restrict__ fm_size,
                                 double* __restrict__ ws) {
    const int id = blockIdx.x * blockDim.x + threadIdx.x;
    float noobj_rm = 0.0f, objs = 0.0f, priors = 0.0f, trues = 0.0f, scorr = 0.0f;

    if (id < BB * TD * AD) {
        int b = id / (TD * AD);
        int r = id % (TD * AD);
        int t = r / AD;
        int a = r % AD;

        const float* to = tobj + (b * TD + t) * 4;
        float tox = to[0] * (1.0f / 32.0f);
        float toy = to[1] * (1.0f / 32.0f);
        float tw  = to[2] * (1.0f / 32.0f);
        float th  = to[3] * (1.0f / 32.0f);
        int ii = (int)floorf(tox);
        int jj = (int)floorf(toy);

        const int cell = (b * WD + ii) * HD + jj;
        const float* p = pred + (cell * AD + a) * 5;
        const int fm = (ii * HD + jj) * 2;
        float px = sigmoidf_(p[0]) + fm_cord[fm + 0];
        float py = sigmoidf_(p[1]) + fm_cord[fm + 1];
        float pw = sigmoidf_(p[2]) * fm_size[fm + 0];
        float ph = sigmoidf_(p[3]) * fm_size[fm + 1];
        float conf = sigmoidf_(p[4]);

        float inter = fminf(pw, tw) * fminf(ph, th);
        float uni = pw * ph + tw * th - inter;
        float iou = inter / uni;

        if (iou > 0.5f) {
            noobj_rm = conf * conf;
            objs = (conf - iou) * (conf - iou);
            float aw = anchors[a * 2 + 0];
            float ah = anchors[a * 2 + 1];
            priors = (pw - aw) * (pw - aw) + (ph - ah) * (ph - ah);
            trues = (px - tox) * (px - tox) + (py - toy) * (py - toy)
                  + (pw - tw) * (pw - tw) + (ph - th) * (ph - th);
            // score replacement at this position:
            // sum(cls - tl)^2 - sum(cls - base)^2 = 2*cls[79] - 2*dot(cls, tl)
            const float* cl = cls + (cell * AD + a) * CD;
            const float* tl = tlab + (b * TD + t) * CD;
            float dot = 0.0f;
            #pragma unroll 8
            for (int c = 0; c < CD; ++c) dot += cl[c] * tl[c];
            scorr = 2.0f * cl[CD - 1] - 2.0f * dot;
        }
    }

    wave_atomic_add(&ws[3], noobj_rm);
    wave_atomic_add(&ws[4], objs);
    wave_atomic_add(&ws[5], priors);
    wave_atomic_add(&ws[6], trues);
    wave_atomic_add(&ws[7], scorr);
}

__global__ void yolo_finalize(const double* __restrict__ ws,
                              const int* __restrict__ epoch_p,
                              float* __restrict__ out) {
    const double n1 = (double)N1;
    double sumsq = ws[0], sum79 = ws[1], conf2 = ws[2];
    double rm = ws[3], objs = ws[4], priors = ws[5], trues = ws[6], scorr = ws[7];

    // epoch is a python int -> int32; hedge against float encoding
    int ev = epoch_p[0];
    double epoch;
    if (ev >= 0 && ev <= 1000000) {
        epoch = (double)ev;
    } else {
        float f = __int_as_float(ev);
        epoch = (double)f;
    }
    double need_prior = (epoch < 10.0) ? 1.0 : 0.0;

    double noobj_loss = 0.25 * (conf2 - rm) / n1;                 // 0.5 * 0.5
    double obj_loss   = 2.5 * objs / n1;                          // 5.0 * 0.5
    double prior_loss = need_prior * 2.5 * priors / (2.0 * n1);
    double true_loss  = 2.5 * trues / (4.0 * n1);
    double score_base = sumsq + n1 - 2.0 * sum79;                 // sum (cls - onehot79)^2
    double score_loss = 2.5 * (score_base + scorr) / (80.0 * n1);

    out[0] = (float)((noobj_loss + obj_loss + prior_loss + true_loss + score_loss) / 4.0);
}

extern "C" void kernel_launch(void* const* d_in, const int* in_sizes, int n_in,
                              void* d_out, int out_size, void* d_ws, size_t ws_size,
                              hipStream_t stream) {
    const int*   epoch   = (const int*)d_in[0];
    const float* cls     = (const float*)d_in[1];
    const float* pred    = (const float*)d_in[2];
    const float* tobj    = (const float*)d_in[3];
    const float* tlab    = (const float*)d_in[4];
    const float* anchors = (const float*)d_in[5];
    const float* fm_cord = (const float*)d_in[6];
    const float* fm_size = (const float*)d_in[7];
    double* ws = (double*)d_ws;
    float* out = (float*)d_out;

    // ws is poisoned to 0xAA before every call — zero the 8 accumulators
    hipMemsetAsync(ws, 0, 8 * sizeof(double), stream);

    yolo_base_reduce<<<1024, 256, 0, stream>>>(cls, pred, ws);

    const int ncorr = BB * TD * AD;  // 25600
    yolo_corrections<<<(ncorr + 255) / 256, 256, 0, stream>>>(
        cls, pred, tobj, tlab, anchors, fm_cord, fm_size, ws);

    yolo_finalize<<<1, 1, 0, stream>>>(ws, epoch, out);
}

// Round 2
// 374.163 us; speedup vs baseline: 1.0628x; 1.0628x over previous
//
#include <hip/hip_runtime.h>
#include <math.h>

// Problem constants (match reference)
#define BB 256
#define WD 19
#define HD 19
#define AD 5
#define CD 80
#define TD 20
#define N1 462080                 // B*W*H*A
#define NCLS (N1 * CD)            // 36,966,400 floats
#define NPRED (N1 * 5)            // 2,310,400 floats

#define NB_BASE 1024
#define NB_CORR 100               // 100*256 = 25600 = B*T*A
#define BASE_THREADS (NB_BASE * 256)   // 262,144
#define UNROLL 8

__device__ __forceinline__ float sigmoidf_(float x) {
    return 1.0f / (1.0f + expf(-x));
}

__device__ __forceinline__ void wave_atomic_add(double* dst, float v) {
    for (int off = 32; off > 0; off >>= 1) v += __shfl_down(v, off, 64);
    if ((threadIdx.x & 63) == 0) atomicAdd(dst, (double)v);
}

// ws layout (doubles):
// [0] sum(cls^2)  [1] sum(cls at c==79)  [2] sum(conf^2) base
// [3] noobj removed  [4] obj  [5] prior  [6] true  [7] score corr
__global__ void __launch_bounds__(256)
yolo_fused(const float* __restrict__ cls,
           const float* __restrict__ pred,
           const float* __restrict__ tobj,
           const float* __restrict__ tlab,
           const float* __restrict__ anchors,
           const float* __restrict__ fm_cord,
           const float* __restrict__ fm_size,
           double* __restrict__ ws) {
    if (blockIdx.x < NB_BASE) {
        // ---------------- streaming base reduction ----------------
        const int tid = blockIdx.x * 256 + threadIdx.x;
        const int stride = BASE_THREADS;
        const int sweep = stride * UNROLL;

        float sumsq = 0.0f, sum79 = 0.0f, conf2 = 0.0f;

        const float4* cls4 = reinterpret_cast<const float4*>(cls);
        const int nc4 = NCLS / 4;                    // 9,241,600
        const int nfull = (nc4 / sweep) * sweep;     // unrolled portion

        for (int base = tid; base < nfull; base += sweep) {
            float4 v[UNROLL];
            #pragma unroll
            for (int k = 0; k < UNROLL; ++k) v[k] = cls4[base + k * stride];
            #pragma unroll
            for (int k = 0; k < UNROLL; ++k) {
                sumsq += v[k].x * v[k].x + v[k].y * v[k].y
                       + v[k].z * v[k].z + v[k].w * v[k].w;
                // element 4i+3, channel (4i+3)%80 == 79  <=>  i%20 == 19
                if (((base + k * stride) % 20) == 19) sum79 += v[k].w;
            }
        }
        for (int i = nfull + tid; i < nc4; i += stride) {
            float4 v = cls4[i];
            sumsq += v.x * v.x + v.y * v.y + v.z * v.z + v.w * v.w;
            if (i % 20 == 19) sum79 += v.w;
        }

        // pred_object conf^2: channel (4i+k)%5 == 4 => k=(i+4)%5
        const float4* p4 = reinterpret_cast<const float4*>(pred);
        const int np4 = NPRED / 4;
        for (int i = tid; i < np4; i += stride) {
            float4 v = p4[i];
            int k = (i + 4) % 5;
            if (k < 4) {
                float x = (k == 0) ? v.x : (k == 1) ? v.y : (k == 2) ? v.z : v.w;
                float c = sigmoidf_(x);
                conf2 += c * c;
            }
        }

        wave_atomic_add(&ws[0], sumsq);
        wave_atomic_add(&ws[1], sum79);
        wave_atomic_add(&ws[2], conf2);
    } else {
        // ---------------- sparse corrections ----------------
        const int id = (blockIdx.x - NB_BASE) * 256 + threadIdx.x;
        float noobj_rm = 0.0f, objs = 0.0f, priors = 0.0f, trues = 0.0f, scorr = 0.0f;

        if (id < BB * TD * AD) {
            int b = id / (TD * AD);
            int r = id % (TD * AD);
            int t = r / AD;
            int a = r % AD;

            const float4 to4 = reinterpret_cast<const float4*>(tobj)[b * TD + t];
            float tox = to4.x * (1.0f / 32.0f);
            float toy = to4.y * (1.0f / 32.0f);
            float tw  = to4.z * (1.0f / 32.0f);
            float th  = to4.w * (1.0f / 32.0f);
            int ii = (int)floorf(tox);
            int jj = (int)floorf(toy);

            const int cell = (b * WD + ii) * HD + jj;
            const float* p = pred + (cell * AD + a) * 5;
            const int fm = (ii * HD + jj) * 2;
            float px = sigmoidf_(p[0]) + fm_cord[fm + 0];
            float py = sigmoidf_(p[1]) + fm_cord[fm + 1];
            float pw = sigmoidf_(p[2]) * fm_size[fm + 0];
            float ph = sigmoidf_(p[3]) * fm_size[fm + 1];
            float conf = sigmoidf_(p[4]);

            float inter = fminf(pw, tw) * fminf(ph, th);
            float uni = pw * ph + tw * th - inter;
            float iou = inter / uni;

            if (iou > 0.5f) {
                noobj_rm = conf * conf;
                objs = (conf - iou) * (conf - iou);
                float aw = anchors[a * 2 + 0];
                float ah = anchors[a * 2 + 1];
                priors = (pw - aw) * (pw - aw) + (ph - ah) * (ph - ah);
                trues = (px - tox) * (px - tox) + (py - toy) * (py - toy)
                      + (pw - tw) * (pw - tw) + (ph - th) * (ph - th);
                // score replacement: sum(cls-tl)^2 - sum(cls-onehot79)^2
                //                  = 2*cls[79] - 2*dot(cls, tl)   (tl one-hot)
                const float4* cl4 = reinterpret_cast<const float4*>(cls + (cell * AD + a) * CD);
                const float4* tl4 = reinterpret_cast<const float4*>(tlab + (b * TD + t) * CD);
                float dot = 0.0f;
                float cl79 = 0.0f;
                #pragma unroll 5
                for (int c = 0; c < CD / 4; ++c) {
                    float4 x = cl4[c];
                    float4 y = tl4[c];
                    dot += x.x * y.x + x.y * y.y + x.z * y.z + x.w * y.w;
                    if (c == CD / 4 - 1) cl79 = x.w;
                }
                scorr = 2.0f * cl79 - 2.0f * dot;
            }
        }

        wave_atomic_add(&ws[3], noobj_rm);
        wave_atomic_add(&ws[4], objs);
        wave_atomic_add(&ws[5], priors);
        wave_atomic_add(&ws[6], trues);
        wave_atomic_add(&ws[7], scorr);
    }
}

__global__ void yolo_finalize(const double* __restrict__ ws,
                              const int* __restrict__ epoch_p,
                              float* __restrict__ out) {
    const double n1 = (double)N1;
    double sumsq = ws[0], sum79 = ws[1], conf2 = ws[2];
    double rm = ws[3], objs = ws[4], priors = ws[5], trues = ws[6], scorr = ws[7];

    int ev = epoch_p[0];
    double epoch;
    if (ev >= 0 && ev <= 1000000) {
        epoch = (double)ev;
    } else {
        float f = __int_as_float(ev);
        epoch = (double)f;
    }
    double need_prior = (epoch < 10.0) ? 1.0 : 0.0;

    double noobj_loss = 0.25 * (conf2 - rm) / n1;
    double obj_loss   = 2.5 * objs / n1;
    double prior_loss = need_prior * 2.5 * priors / (2.0 * n1);
    double true_loss  = 2.5 * trues / (4.0 * n1);
    double score_base = sumsq + n1 - 2.0 * sum79;
    double score_loss = 2.5 * (score_base + scorr) / (80.0 * n1);

    out[0] = (float)((noobj_loss + obj_loss + prior_loss + true_loss + score_loss) / 4.0);
}

extern "C" void kernel_launch(void* const* d_in, const int* in_sizes, int n_in,
                              void* d_out, int out_size, void* d_ws, size_t ws_size,
                              hipStream_t stream) {
    const int*   epoch   = (const int*)d_in[0];
    const float* cls     = (const float*)d_in[1];
    const float* pred    = (const float*)d_in[2];
    const float* tobj    = (const float*)d_in[3];
    const float* tlab    = (const float*)d_in[4];
    const float* anchors = (const float*)d_in[5];
    const float* fm_cord = (const float*)d_in[6];
    const float* fm_size = (const float*)d_in[7];
    double* ws = (double*)d_ws;
    float* out = (float*)d_out;

    hipMemsetAsync(ws, 0, 8 * sizeof(double), stream);

    yolo_fused<<<NB_BASE + NB_CORR, 256, 0, stream>>>(
        cls, pred, tobj, tlab, anchors, fm_cord, fm_size, ws);

    yolo_finalize<<<1, 1, 0, stream>>>(ws, epoch, out);
}